// Round 1
// baseline (193.380 us; speedup 1.0000x reference)
//
#include <hip/hip_runtime.h>
#include <math.h>

#define CC 5
#define DM 512
#define UU 50
#define NOUT 1048576   // 8*8*256*64

__device__ __forceinline__ float gelu_exact(float x) {
    return 0.5f * x * (1.0f + erff(x * 0.70710678118654752f));
}

// sign-aware float atomic max (init must be -inf)
__device__ __forceinline__ void atomicMaxFloat(float* addr, float value) {
    if (value >= 0.0f) {
        atomicMax((int*)addr, __float_as_int(value));
    } else {
        atomicMin((unsigned int*)addr, __float_as_uint(value));
    }
}

__global__ void init_out(float* __restrict__ out) {
    int i = blockIdx.x * 256 + threadIdx.x;
    if (i < NOUT) out[i] = -INFINITY;
}

__global__ __launch_bounds__(256) void cluster_main(
    const float* __restrict__ K,
    const float* __restrict__ Wk, const float* __restrict__ bk,
    const float* __restrict__ Wq, const float* __restrict__ bq,
    const float* __restrict__ Wback, const float* __restrict__ bback,
    float* __restrict__ out, float* __restrict__ ws_mu, float* __restrict__ ws_lp)
{
    const int blk  = blockIdx.x;       // b*256 + l'
    const int b    = blk >> 8;
    const int lp   = blk & 255;
    const int h    = lp >> 5;
    const int l0   = (lp & 31) * 8;
    const int tid  = threadIdx.x;
    const int wave = tid >> 6;
    const int lane = tid & 63;

    __shared__ float Wk_sh[DM * CC];
    __shared__ float Wq_sh[DM * CC];
    __shared__ float Ksh[7 * 8 * 64];
    __shared__ float Sw[4][CC];
    __shared__ float Scw[4][CC][CC];
    __shared__ float lpw[4];
    __shared__ float centers[CC][CC];

    for (int i = tid; i < DM * CC; i += 256) {
        Wk_sh[i] = Wk[i];
        Wq_sh[i] = Wq[i];
    }
    // stage K[b', h, l0+s, d] for b' = 1..b  (b*512 floats)
    const int nk = b * 512;
    for (int i = tid; i < nk; i += 256) {
        int bp = (i >> 9) + 1;
        int s  = (i >> 6) & 7;
        int d  = i & 63;
        Ksh[i] = K[(((bp * 8 + h) * 256) + (l0 + s)) * 64 + d];
    }
    if (tid < 20)  Sw[tid / 5][tid % 5] = 0.0f;
    if (tid < 100) Scw[tid / 25][(tid / 5) % 5][tid % 5] = 0.0f;
    if (tid < 4)   lpw[tid] = 0.0f;

    float bkv[CC], bqv[CC];
    #pragma unroll
    for (int c = 0; c < CC; ++c) { bkv[c] = bk[c]; bqv[c] = bq[c]; }

    __syncthreads();

    const int ulo = 50 - b;  // u_src >= ulo => nonzero
    for (int u = wave; u < UU; u += 4) {
        float ak[CC] = {0,0,0,0,0}, aq[CC] = {0,0,0,0,0};
        #pragma unroll
        for (int k = 0; k < 8; ++k) {
            int m = lane + k * 64;
            int q = u * 512 + m;
            int s = q / 3200;
            int r2 = q - s * 3200;
            int d = r2 / 50;
            int usrc = r2 - d * 50;
            float x = 0.0f;
            if (usrc >= ulo) x = Ksh[((b + usrc - 50) * 8 + s) * 64 + d];
            #pragma unroll
            for (int c = 0; c < CC; ++c) {
                ak[c] = fmaf(x, Wk_sh[m * 5 + c], ak[c]);
                aq[c] = fmaf(x, Wq_sh[m * 5 + c], aq[c]);
            }
        }
        // butterfly reduce: all lanes end with full 512-dots
        #pragma unroll
        for (int off = 1; off < 64; off <<= 1) {
            #pragma unroll
            for (int c = 0; c < CC; ++c) {
                ak[c] += __shfl_xor(ak[c], off, 64);
                aq[c] += __shfl_xor(aq[c], off, 64);
            }
        }
        // gelu + softmax (both heads), computed redundantly on all lanes
        float gk[CC], gq[CC];
        float mk = -1e30f, mq = -1e30f;
        #pragma unroll
        for (int c = 0; c < CC; ++c) {
            gk[c] = gelu_exact(ak[c] + bkv[c]); mk = fmaxf(mk, gk[c]);
            gq[c] = gelu_exact(aq[c] + bqv[c]); mq = fmaxf(mq, gq[c]);
        }
        float sk = 0.0f, sq = 0.0f;
        #pragma unroll
        for (int c = 0; c < CC; ++c) {
            gk[c] = expf(gk[c] - mk); sk += gk[c];
            gq[c] = expf(gq[c] - mq); sq += gq[c];
        }
        float rsk = 1.0f / sk, rsq = 1.0f / sq;
        float qv[CC], kv[CC];
        float sumq = 0.0f, sumk = 0.0f;
        #pragma unroll
        for (int c = 0; c < CC; ++c) {
            kv[c] = gk[c] * rsk; sumk += kv[c];
            qv[c] = gq[c] * rsq; sumq += qv[c];
        }
        float mu = sumq * 0.2f;
        float xb = sumk * 0.2f;
        float var = 0.0f;
        #pragma unroll
        for (int c = 0; c < CC; ++c) { float dq = qv[c] - mu; var = fmaf(dq, dq, var); }
        var *= 0.25f;                       // ddof=1
        float sd = sqrtf(var);
        float sigma = log1pf(expf(sd));     // softplus
        float z = (xb - mu) / sigma;
        float logp = -0.5f * z * z - logf(sigma) - 0.91893853320467274f;
        int ind = 0; float bv = qv[0];
        #pragma unroll
        for (int c = 1; c < CC; ++c) if (qv[c] > bv) { bv = qv[c]; ind = c; }
        if (lane == 0) {
            #pragma unroll
            for (int c = 0; c < CC; ++c) Sw[wave][c] += qv[c];
            #pragma unroll
            for (int c = 0; c < CC; ++c) Scw[wave][ind][c] += qv[c];
            lpw[wave] += logp;
            ws_mu[(b * 50 + u) * 256 + lp] = mu;
        }
    }
    __syncthreads();

    if (tid == 0) ws_lp[blk] = lpw[0] + lpw[1] + lpw[2] + lpw[3];
    if (tid < 25) {
        int c = tid / 5, j = tid % 5;
        float s  = Sw[0][j] + Sw[1][j] + Sw[2][j] + Sw[3][j];
        float sc = Scw[0][c][j] + Scw[1][c][j] + Scw[2][c][j] + Scw[3][c][j];
        centers[c][j] = (s - sc) * 0.02f;   // /50
    }
    __syncthreads();

    // cc = gelu(centers @ W_back + b_back), scatter-max into out
    const int base_p = b * 131072 + lp * 512;
    for (int idx = tid; idx < CC * DM; idx += 256) {
        int c = idx >> 9;
        int m = idx & 511;
        float v = bback[m];
        #pragma unroll
        for (int j = 0; j < CC; ++j) v = fmaf(centers[c][j], Wback[j * 512 + m], v);
        v = gelu_exact(v);
        int p = c * 1048576 + base_p + m;
        int o = (p / 655360) * 131072 + ((p % 655360) / 81920) * 16384 + (p & 16383);
        atomicMaxFloat(out + o, v);
    }
}

__global__ __launch_bounds__(1024) void finalize(
    const float* __restrict__ ws_mu, const float* __restrict__ ws_lp,
    float* __restrict__ out)
{
    const int tid  = threadIdx.x;
    const int wave = tid >> 6;   // 0..15
    const int lane = tid & 63;
    __shared__ float red[1024];
    __shared__ float total_lp_sh;
    __shared__ float cew[16];

    red[tid] = ws_lp[tid] + ws_lp[tid + 1024];
    __syncthreads();
    for (int s = 512; s > 0; s >>= 1) {
        if (tid < s) red[tid] += red[tid + s];
        __syncthreads();
    }
    if (tid == 0) total_lp_sh = red[0];

    // CE over l-axis: 400 (b,u) pairs, one wave per pair
    float ce_part = 0.0f;
    for (int pair = wave; pair < 400; pair += 16) {
        const float* mp = ws_mu + pair * 256;
        float v0 = mp[lane], v1 = mp[lane + 64], v2 = mp[lane + 128], v3 = mp[lane + 192];
        float mx = fmaxf(fmaxf(v0, v1), fmaxf(v2, v3));
        #pragma unroll
        for (int off = 1; off < 64; off <<= 1) mx = fmaxf(mx, __shfl_xor(mx, off, 64));
        float se = expf(v0 - mx) + expf(v1 - mx) + expf(v2 - mx) + expf(v3 - mx);
        #pragma unroll
        for (int off = 1; off < 64; off <<= 1) se += __shfl_xor(se, off, 64);
        float lse = mx + logf(se);
        float a = -(v0 * (v0 - lse) + v1 * (v1 - lse) + v2 * (v2 - lse) + v3 * (v3 - lse));
        #pragma unroll
        for (int off = 1; off < 64; off <<= 1) a += __shfl_xor(a, off, 64);
        ce_part += a;
    }
    if (lane == 0) cew[wave] = ce_part;
    __syncthreads();
    if (tid == 0) {
        float ce = 0.0f;
        #pragma unroll
        for (int w = 0; w < 16; ++w) ce += cew[w];
        ce *= (1.0f / 400.0f);
        float loss = -(total_lp_sh * (1.0f / 102400.0f)) + ce;
        out[NOUT] = loss;
    }
}

extern "C" void kernel_launch(void* const* d_in, const int* in_sizes, int n_in,
                              void* d_out, int out_size, void* d_ws, size_t ws_size,
                              hipStream_t stream) {
    const float* K  = (const float*)d_in[0];
    // d_in[1] = V, unused by the reference
    const float* Wk = (const float*)d_in[2];
    const float* bk = (const float*)d_in[3];
    const float* Wq = (const float*)d_in[4];
    const float* bq = (const float*)d_in[5];
    const float* Wb = (const float*)d_in[6];
    const float* bb = (const float*)d_in[7];
    float* out   = (float*)d_out;
    float* ws_mu = (float*)d_ws;          // 102400 floats, layout [b][u][l]
    float* ws_lp = ws_mu + 102400;        // 2048 floats, per-block logprob partials

    init_out<<<NOUT / 256, 256, 0, stream>>>(out);
    cluster_main<<<2048, 256, 0, stream>>>(K, Wk, bk, Wq, bq, Wb, bb, out, ws_mu, ws_lp);
    finalize<<<1, 1024, 0, stream>>>(ws_mu, ws_lp, out);
}

// Round 2
// 62.602 us; speedup vs baseline: 3.0890x; 3.0890x over previous
//
#include <hip/hip_runtime.h>
#include <math.h>

#define CC 5
#define NOUT 1048576   // 8*8*256*64

__device__ __forceinline__ float gelu_exact(float x) {
    return 0.5f * x * (1.0f + erff(x * 0.70710678118654752f));
}

// ---------------------------------------------------------------------------
// Kernel 1: per-unit (b,lp) sparse clustering.
//   grid 512 x 256. Wave w of block bid handles unit = w*512 + bid  (2048 units).
//   Lane u (< 50) computes row u of K_unf sparsely, softmax(gelu(.)) for both
//   heads, per-row stats; epilogue reduces centers/logp via per-wave LDS.
// ---------------------------------------------------------------------------
__global__ __launch_bounds__(256) void cluster_main(
    const float* __restrict__ K,
    const float* __restrict__ Wk, const float* __restrict__ bk,
    const float* __restrict__ Wq, const float* __restrict__ bq,
    float* __restrict__ ws_mu, float* __restrict__ ws_lp, float* __restrict__ ws_ctr)
{
    const int tid  = threadIdx.x;
    const int wave = tid >> 6;
    const int lane = tid & 63;
    const int unit = wave * 512 + blockIdx.x;   // balanced b across waves
    const int b    = unit >> 8;
    const int lp   = unit & 255;
    const int h    = lp >> 5;
    const int l0   = (lp & 31) << 3;

    __shared__ float4 WW4[512 * 3];   // row m: [wk0..3][wk4,wq0..2][wq3,wq4,0,0]
    __shared__ float  Ksh[4][3584];   // per-wave K stage, sd-major stride b

    for (int m = tid; m < 512; m += 256) {
        const float* wkp = Wk + m * 5;
        const float* wqp = Wq + m * 5;
        WW4[m * 3 + 0] = make_float4(wkp[0], wkp[1], wkp[2], wkp[3]);
        WW4[m * 3 + 1] = make_float4(wkp[4], wqp[0], wqp[1], wqp[2]);
        WW4[m * 3 + 2] = make_float4(wqp[3], wqp[4], 0.f, 0.f);
    }
    __syncthreads();

    float* ksh = Ksh[wave];
    // stage: ksh[sd*b + bp] = K[bp+1, h, l0 + (sd>>6), sd&63]   (coalesced reads)
    const int nk = b << 9;
    for (int i = lane; i < nk; i += 64) {
        int bp = i >> 9, sd = i & 511;
        ksh[sd * b + bp] = K[((((bp + 1) * 8 + h) * 256) + (l0 + (sd >> 6))) * 64 + (sd & 63)];
    }

    const int u = lane;
    if (u < 50) {
        float ak[CC], aq[CC];
        #pragma unroll
        for (int c = 0; c < CC; ++c) { ak[c] = bk[c]; aq[c] = bq[c]; }

        const int q0 = u << 9;
        const int r0 = q0 % 50;
        const int start = (50 - b) - r0;          // may be <= 0 (partial first run)
        int B = q0 / 50;                           // = s*64 + d for current run
        for (int st = start; st < 512; st += 50, ++B) {
            int jlo = st < 0 ? -st : 0;
            int jhi = min(b, 512 - st);
            const float* kp = ksh + B * b;
            for (int j = jlo; j < jhi; ++j) {
                float x = kp[j];
                int mm = (st + j) * 3;
                float4 w0 = WW4[mm], w1 = WW4[mm + 1], w2 = WW4[mm + 2];
                ak[0] = fmaf(x, w0.x, ak[0]);
                ak[1] = fmaf(x, w0.y, ak[1]);
                ak[2] = fmaf(x, w0.z, ak[2]);
                ak[3] = fmaf(x, w0.w, ak[3]);
                ak[4] = fmaf(x, w1.x, ak[4]);
                aq[0] = fmaf(x, w1.y, aq[0]);
                aq[1] = fmaf(x, w1.z, aq[1]);
                aq[2] = fmaf(x, w1.w, aq[2]);
                aq[3] = fmaf(x, w2.x, aq[3]);
                aq[4] = fmaf(x, w2.y, aq[4]);
            }
        }

        // gelu + softmax both heads (lane-local)
        float gk[CC], gq[CC];
        float mk = -1e30f, mq = -1e30f;
        #pragma unroll
        for (int c = 0; c < CC; ++c) {
            gk[c] = gelu_exact(ak[c]); mk = fmaxf(mk, gk[c]);
            gq[c] = gelu_exact(aq[c]); mq = fmaxf(mq, gq[c]);
        }
        float sk = 0.f, sq = 0.f;
        #pragma unroll
        for (int c = 0; c < CC; ++c) {
            gk[c] = expf(gk[c] - mk); sk += gk[c];
            gq[c] = expf(gq[c] - mq); sq += gq[c];
        }
        float rsk = 1.f / sk, rsq = 1.f / sq;
        float qv[CC];
        float sumq = 0.f, sumk = 0.f;
        #pragma unroll
        for (int c = 0; c < CC; ++c) {
            float kvc = gk[c] * rsk; sumk += kvc;
            qv[c] = gq[c] * rsq;     sumq += qv[c];
        }
        float mu = sumq * 0.2f;
        float xb = sumk * 0.2f;
        float var = 0.f;
        #pragma unroll
        for (int c = 0; c < CC; ++c) { float dq = qv[c] - mu; var = fmaf(dq, dq, var); }
        var *= 0.25f;                         // ddof=1
        float sd_ = sqrtf(var);
        float sigma = log1pf(expf(sd_));      // softplus
        float z = (xb - mu) / sigma;
        float logp = -0.5f * z * z - logf(sigma) - 0.91893853320467274f;
        int ind = 0; float bv = qv[0];
        #pragma unroll
        for (int c = 1; c < CC; ++c) if (qv[c] > bv) { bv = qv[c]; ind = c; }

        ws_mu[(b * 50 + u) * 256 + lp] = mu;

        // per-wave transpose into (dead) ksh region: row u = {qv0..4, ind, logp}
        float* row = ksh + u * 7;
        #pragma unroll
        for (int c = 0; c < CC; ++c) row[c] = qv[c];
        row[5] = (float)ind;
        row[6] = logp;
    }

    // same-wave LDS ordering: drain DS queue, block compiler reordering
    asm volatile("s_waitcnt lgkmcnt(0)" ::: "memory");

    const int t = lane;
    if (t < 26) {
        const float fi = (float)(t / 5);
        const int sel = (t < 25) ? (t % 5) : 6;
        const bool always = (t == 25);
        float acc = 0.f;
        for (int u2 = 0; u2 < 50; ++u2) {
            float v = ksh[u2 * 7 + sel];
            float f = ksh[u2 * 7 + 5];
            acc += (always || f != fi) ? v : 0.f;
        }
        if (t < 25) ws_ctr[unit * 25 + t] = acc * 0.02f;   // mean over 50 (masked-zero)
        else        ws_lp[unit] = acc;
    }
}

// ---------------------------------------------------------------------------
// Kernel 2: out[o] = max_{c2} gelu(centers[unit(c2)][c(c2)] . Wback[:,m] + bb[m])
//   Atomic-free: each output gathers its 5 candidates directly.
// ---------------------------------------------------------------------------
__global__ __launch_bounds__(256) void backmap(
    const float* __restrict__ Wb, const float* __restrict__ bb,
    const float* __restrict__ ws_ctr, float* __restrict__ out)
{
    const int o = blockIdx.x * 256 + threadIdx.x;
    const int b2  = o >> 17;
    const int h2  = (o >> 14) & 7;
    const int r14 = o & 16383;
    const int m   = r14 & 511;
    const float w0 = Wb[m], w1 = Wb[512 + m], w2 = Wb[1024 + m], w3 = Wb[1536 + m], w4 = Wb[2048 + m];
    const float bias = bb[m];
    const int pbase = b2 * 655360 + h2 * 81920 + r14;
    float best = -INFINITY;
    #pragma unroll
    for (int c2 = 0; c2 < 5; ++c2) {
        int p = pbase + c2 * 16384;
        int c = p >> 20;
        int unit = (p & 1048575) >> 9;
        const float* ct = ws_ctr + unit * 25 + c * 5;
        float v = bias;
        v = fmaf(ct[0], w0, v);
        v = fmaf(ct[1], w1, v);
        v = fmaf(ct[2], w2, v);
        v = fmaf(ct[3], w3, v);
        v = fmaf(ct[4], w4, v);
        v = gelu_exact(v);
        best = fmaxf(best, v);
    }
    out[o] = best;
}

// ---------------------------------------------------------------------------
// Kernel 3: loss = -mean(logprob) + CE  (CE: log-softmax over l axis of mu)
// ---------------------------------------------------------------------------
__global__ __launch_bounds__(1024) void finalize(
    const float* __restrict__ ws_mu, const float* __restrict__ ws_lp,
    float* __restrict__ out)
{
    const int tid  = threadIdx.x;
    const int wave = tid >> 6;   // 0..15
    const int lane = tid & 63;
    __shared__ float red[1024];
    __shared__ float total_lp_sh;
    __shared__ float cew[16];

    red[tid] = ws_lp[tid] + ws_lp[tid + 1024];
    __syncthreads();
    for (int s = 512; s > 0; s >>= 1) {
        if (tid < s) red[tid] += red[tid + s];
        __syncthreads();
    }
    if (tid == 0) total_lp_sh = red[0];

    float ce_part = 0.0f;
    for (int pair = wave; pair < 400; pair += 16) {
        const float* mp = ws_mu + pair * 256;
        float v0 = mp[lane], v1 = mp[lane + 64], v2 = mp[lane + 128], v3 = mp[lane + 192];
        float mx = fmaxf(fmaxf(v0, v1), fmaxf(v2, v3));
        #pragma unroll
        for (int off = 1; off < 64; off <<= 1) mx = fmaxf(mx, __shfl_xor(mx, off, 64));
        float se = expf(v0 - mx) + expf(v1 - mx) + expf(v2 - mx) + expf(v3 - mx);
        #pragma unroll
        for (int off = 1; off < 64; off <<= 1) se += __shfl_xor(se, off, 64);
        float lse = mx + logf(se);
        float a = -(v0 * (v0 - lse) + v1 * (v1 - lse) + v2 * (v2 - lse) + v3 * (v3 - lse));
        #pragma unroll
        for (int off = 1; off < 64; off <<= 1) a += __shfl_xor(a, off, 64);
        ce_part += a;
    }
    if (lane == 0) cew[wave] = ce_part;
    __syncthreads();
    if (tid == 0) {
        float ce = 0.0f;
        #pragma unroll
        for (int w = 0; w < 16; ++w) ce += cew[w];
        ce *= (1.0f / 400.0f);
        float loss = -(total_lp_sh * (1.0f / 102400.0f)) + ce;
        out[NOUT] = loss;
    }
}

extern "C" void kernel_launch(void* const* d_in, const int* in_sizes, int n_in,
                              void* d_out, int out_size, void* d_ws, size_t ws_size,
                              hipStream_t stream) {
    const float* K  = (const float*)d_in[0];
    // d_in[1] = V, unused by the reference
    const float* Wk = (const float*)d_in[2];
    const float* bk = (const float*)d_in[3];
    const float* Wq = (const float*)d_in[4];
    const float* bq = (const float*)d_in[5];
    const float* Wb = (const float*)d_in[6];
    const float* bb = (const float*)d_in[7];
    float* out    = (float*)d_out;
    float* ws_mu  = (float*)d_ws;            // 102400 floats  [b][u][lp]
    float* ws_lp  = ws_mu + 102400;          // 2048 floats    per-unit logp sums
    float* ws_ctr = ws_lp + 2048;            // 2048*25 floats per-unit centers

    cluster_main<<<512, 256, 0, stream>>>(K, Wk, bk, Wq, bq, ws_mu, ws_lp, ws_ctr);
    backmap<<<NOUT / 256, 256, 0, stream>>>(Wb, bb, ws_ctr, out);
    finalize<<<1, 1024, 0, stream>>>(ws_mu, ws_lp, out);
}